// Round 1
// baseline (262.642 us; speedup 1.0000x reference)
//
#include <hip/hip_runtime.h>
#include <hip/hip_bf16.h>
#include <hip/hip_cooperative_groups.h>

namespace cg = cooperative_groups;

#define NN 8192
constexpr int   STEPS = 10;
constexpr float ALPHA = 0.5f;
constexpr float EPSV  = 1e-10f;

typedef float f32x2 __attribute__((ext_vector_type(2)));
typedef float f32x4 __attribute__((ext_vector_type(4)));

static __device__ __forceinline__ unsigned int f2bf(float f) {
    unsigned int u = __float_as_uint(f);
    return (u + 0x7FFFu + ((u >> 16) & 1u)) >> 16;
}
static __device__ __forceinline__ float bf2f(unsigned int h) {
    return __uint_as_float(h << 16);
}

// ---- Fused: updated_adj = M*adj (nt), adj->fp8 copy, rowsum. One row/block ----
// Near fabric-roofline (5.7 TB/s incl. L3-served M) — unchanged this round.
__global__ __launch_bounds__(256) void k_fused_prep(
        const float* __restrict__ adj, const float* __restrict__ M,
        float* __restrict__ out, unsigned char* __restrict__ a8,
        float* __restrict__ rowsum) {
    const int row = blockIdx.x;
    const int t   = threadIdx.x;
    const float* arow = adj + (size_t)row * NN;
    const float* mrow = M   + (size_t)row * NN;
    float*       orow = out + (size_t)row * NN;
    unsigned char* brow = a8 + (size_t)row * NN;
    float acc = 0.0f;
#pragma unroll
    for (int g = 0; g < 2; ++g) {
        f32x4 v[4], m[4];
#pragma unroll
        for (int k = 0; k < 4; ++k) {
            const int j = (g * 4 + k) * 1024 + t * 4;
            v[k] = __builtin_nontemporal_load((const f32x4*)(arow + j));
        }
#pragma unroll
        for (int k = 0; k < 4; ++k) {
            const int j = (g * 4 + k) * 1024 + t * 4;
            m[k] = __builtin_nontemporal_load((const f32x4*)(mrow + j));
        }
#pragma unroll
        for (int k = 0; k < 4; ++k) {
            const int j = (g * 4 + k) * 1024 + t * 4;
            f32x4 r = v[k] * m[k];
            __builtin_nontemporal_store(r, (f32x4*)(orow + j));
            acc += (v[k].x + v[k].y) + (v[k].z + v[k].w);
            int p = __builtin_amdgcn_cvt_pk_fp8_f32(v[k].x, v[k].y, 0, false);
            p     = __builtin_amdgcn_cvt_pk_fp8_f32(v[k].z, v[k].w, p, true);
            *(unsigned int*)(brow + j) = (unsigned int)p;
        }
    }
#pragma unroll
    for (int o = 32; o > 0; o >>= 1) acc += __shfl_down(acc, o);
    __shared__ float red[4];
    if ((t & 63) == 0) red[t >> 6] = acc;
    __syncthreads();
    if (t == 0) rowsum[row] = (red[0] + red[1]) + (red[2] + red[3]);
}

// ---- Fallback pass 1: row sums only ----
__global__ __launch_bounds__(256) void k_rowsum(
        const float* __restrict__ adj, float* __restrict__ rowsum) {
    const int row = blockIdx.x;
    const int t   = threadIdx.x;
    const float* arow = adj + (size_t)row * NN;
    float acc = 0.0f;
#pragma unroll
    for (int c = 0; c < 8; ++c) {
        const int j = c * 1024 + t * 4;
        float4 v = *(const float4*)(arow + j);
        acc += (v.x + v.y) + (v.z + v.w);
    }
#pragma unroll
    for (int o = 32; o > 0; o >>= 1) acc += __shfl_down(acc, o);
    __shared__ float red[4];
    if ((t & 63) == 0) red[t >> 6] = acc;
    __syncthreads();
    if (t == 0) rowsum[row] = (red[0] + red[1]) + (red[2] + red[3]);
}

// ---- init: d = rowsum^-1/2, x0 = 1-pos, z0 = bf16(d*x0) (+f32 copy) ----
__global__ __launch_bounds__(256) void k_init(
        const float* __restrict__ rowsum, const float* __restrict__ pos,
        float* __restrict__ d, float* __restrict__ x,
        unsigned short* __restrict__ zbf, float* __restrict__ zf) {
    const int i = blockIdx.x * 256 + threadIdx.x;
    const float dv = rsqrtf(rowsum[i]);
    const float xv = 1.0f - pos[i];
    const float zv = dv * xv;
    d[i] = dv;
    x[i] = xv;
    zbf[i] = (unsigned short)f2bf(zv);
    zf[i] = zv;
}

// ---- Persistent cooperative kernel: init + 10 fp8 steps + loss ----
// 1024 blocks x 256 threads (4 blocks/CU co-resident), 8 rows/block/step.
// Removes 11 kernel launches + per-launch L2 invalidates from the step chain.
__global__ __launch_bounds__(256, 4) void k_coop(
        const unsigned char* __restrict__ a8, const float* __restrict__ rowsum,
        const float* __restrict__ pos, float* __restrict__ d,
        float* __restrict__ x_a, float* __restrict__ x_b,
        unsigned short* __restrict__ zb_a, unsigned short* __restrict__ zb_b,
        float* __restrict__ loss_out) {
    cg::grid_group grid = cg::this_grid();
    const int t = threadIdx.x;
    const int b = blockIdx.x;
    __shared__ float red[8][4];

    // ---- init phase (blocks 0..31 cover all 8192 rows) ----
    if (b < NN / 256) {
        const int i = b * 256 + t;
        const float dv = rsqrtf(rowsum[i]);
        const float xv = 1.0f - pos[i];
        d[i]   = dv;
        x_a[i] = xv;
        zb_a[i] = (unsigned short)f2bf(dv * xv);
    }
    grid.sync();

    float* xi = x_a; float* xo = x_b;
    unsigned short* zi = zb_a; unsigned short* zo = zb_b;
    const int j  = t * 32;        // byte/element offset within a row
    const int r0 = b * 8;         // 8 rows per block

    for (int s = 0; s < STEPS; ++s) {
        // unpack this thread's 32 z values (bf16 -> f32), fully static indexing
        float zf[32];
#pragma unroll
        for (int k = 0; k < 4; ++k) {
            const uint4 q = *(const uint4*)(zi + j + 8 * k);
            zf[k * 8 + 0] = bf2f(q.x & 0xFFFFu); zf[k * 8 + 1] = bf2f(q.x >> 16);
            zf[k * 8 + 2] = bf2f(q.y & 0xFFFFu); zf[k * 8 + 3] = bf2f(q.y >> 16);
            zf[k * 8 + 4] = bf2f(q.z & 0xFFFFu); zf[k * 8 + 5] = bf2f(q.z >> 16);
            zf[k * 8 + 6] = bf2f(q.w & 0xFFFFu); zf[k * 8 + 7] = bf2f(q.w >> 16);
        }
#pragma unroll
        for (int h2 = 0; h2 < 2; ++h2) {
            uint4 pa[4][2];
#pragma unroll
            for (int r = 0; r < 4; ++r) {
                const unsigned char* arow = a8 + (size_t)(r0 + h2 * 4 + r) * NN + j;
                pa[r][0] = *(const uint4*)(arow);
                pa[r][1] = *(const uint4*)(arow + 16);
            }
            float acc0 = 0.0f, acc1 = 0.0f, acc2 = 0.0f, acc3 = 0.0f;
#pragma unroll
            for (int r = 0; r < 4; ++r) {
                const unsigned int w[8] = {pa[r][0].x, pa[r][0].y, pa[r][0].z, pa[r][0].w,
                                           pa[r][1].x, pa[r][1].y, pa[r][1].z, pa[r][1].w};
                float a = 0.0f;
#pragma unroll
                for (int wi = 0; wi < 8; ++wi) {
                    f32x2 lo = __builtin_amdgcn_cvt_pk_f32_fp8((int)w[wi], false);
                    f32x2 hi = __builtin_amdgcn_cvt_pk_f32_fp8((int)w[wi], true);
                    a = fmaf(lo[0], zf[wi * 4 + 0], a);
                    a = fmaf(lo[1], zf[wi * 4 + 1], a);
                    a = fmaf(hi[0], zf[wi * 4 + 2], a);
                    a = fmaf(hi[1], zf[wi * 4 + 3], a);
                }
                if (r == 0) acc0 += a; else if (r == 1) acc1 += a;
                else if (r == 2) acc2 += a; else acc3 += a;
            }
#pragma unroll
            for (int o = 32; o > 0; o >>= 1) {
                acc0 += __shfl_down(acc0, o);
                acc1 += __shfl_down(acc1, o);
                acc2 += __shfl_down(acc2, o);
                acc3 += __shfl_down(acc3, o);
            }
            if ((t & 63) == 0) {
                const int w = t >> 6;
                red[h2 * 4 + 0][w] = acc0; red[h2 * 4 + 1][w] = acc1;
                red[h2 * 4 + 2][w] = acc2; red[h2 * 4 + 3][w] = acc3;
            }
        }
        __syncthreads();
        if (t < 8) {
            const int row = r0 + t;
            const float y  = (red[t][0] + red[t][1]) + (red[t][2] + red[t][3]);
            const float dv = d[row];
            const float xn = ALPHA * dv * y + (1.0f - ALPHA) * xi[row];
            xo[row] = xn;
            zo[row] = (unsigned short)f2bf(dv * xn);
        }
        grid.sync();
        { float* tx = xi; xi = xo; xo = tx; }
        { unsigned short* tz = zi; zi = zo; zo = tz; }
    }

    // ---- loss phase (block 0 only; x/pos are 32 KB each -> L2-hit) ----
    if (b == 0) {
        float sn = 0.0f, sd = 0.0f;
#pragma unroll
        for (int c = 0; c < 8; ++c) {
            const int i4 = c * 256 + t;
            const float4 p  = *(const float4*)(pos + i4 * 4);
            const float4 xv = *(const float4*)(xi  + i4 * 4);
            sn += p.x * logf(1.0f - xv.x + EPSV);
            sn += p.y * logf(1.0f - xv.y + EPSV);
            sn += p.z * logf(1.0f - xv.z + EPSV);
            sn += p.w * logf(1.0f - xv.w + EPSV);
            sd += (p.x + p.y) + (p.z + p.w);
        }
#pragma unroll
        for (int o = 32; o > 0; o >>= 1) {
            sn += __shfl_down(sn, o);
            sd += __shfl_down(sd, o);
        }
        if ((t & 63) == 0) { red[0][t >> 6] = sn; red[1][t >> 6] = sd; }
        __syncthreads();
        if (t == 0) {
            const float n  = (red[0][0] + red[0][1]) + (red[0][2] + red[0][3]);
            const float dd = (red[1][0] + red[1][1]) + (red[1][2] + red[1][3]);
            loss_out[0] = -n / dd;
        }
    }
}

// ---- fp8 step, 4 rows per 256-thread block (fallback path) ----
__global__ __launch_bounds__(256) void k_step_fp8(
        const unsigned char* __restrict__ a8, const float* __restrict__ d,
        const float* __restrict__ xin, const unsigned short* __restrict__ zin,
        float* __restrict__ xout, unsigned short* __restrict__ zout) {
    const int r0 = blockIdx.x * 4;
    const int t  = threadIdx.x;
    const int j  = t * 32;

    uint4 pa[4][2];
#pragma unroll
    for (int r = 0; r < 4; ++r) {
        const unsigned char* arow = a8 + (size_t)(r0 + r) * NN + j;
        pa[r][0] = *(const uint4*)(arow);
        pa[r][1] = *(const uint4*)(arow + 16);
    }
    uint4 zp[4];
#pragma unroll
    for (int k = 0; k < 4; ++k)
        zp[k] = *(const uint4*)(zin + j + 8 * k);

    float acc0 = 0.0f, acc1 = 0.0f, acc2 = 0.0f, acc3 = 0.0f;
#pragma unroll
    for (int h = 0; h < 2; ++h) {
        float zf[16];
#pragma unroll
        for (int k = 0; k < 2; ++k) {
            uint4 q = zp[2 * h + k];
            zf[k * 8 + 0] = bf2f(q.x & 0xFFFFu); zf[k * 8 + 1] = bf2f(q.x >> 16);
            zf[k * 8 + 2] = bf2f(q.y & 0xFFFFu); zf[k * 8 + 3] = bf2f(q.y >> 16);
            zf[k * 8 + 4] = bf2f(q.z & 0xFFFFu); zf[k * 8 + 5] = bf2f(q.z >> 16);
            zf[k * 8 + 6] = bf2f(q.w & 0xFFFFu); zf[k * 8 + 7] = bf2f(q.w >> 16);
        }
#pragma unroll
        for (int r = 0; r < 4; ++r) {
            const uint4 p = pa[r][h];
            unsigned int w[4] = {p.x, p.y, p.z, p.w};
            float a = 0.0f;
#pragma unroll
            for (int wi = 0; wi < 4; ++wi) {
                f32x2 lo = __builtin_amdgcn_cvt_pk_f32_fp8((int)w[wi], false);
                f32x2 hi = __builtin_amdgcn_cvt_pk_f32_fp8((int)w[wi], true);
                a = fmaf(lo[0], zf[wi * 4 + 0], a);
                a = fmaf(lo[1], zf[wi * 4 + 1], a);
                a = fmaf(hi[0], zf[wi * 4 + 2], a);
                a = fmaf(hi[1], zf[wi * 4 + 3], a);
            }
            if (r == 0) acc0 += a; else if (r == 1) acc1 += a;
            else if (r == 2) acc2 += a; else acc3 += a;
        }
    }
#pragma unroll
    for (int o = 32; o > 0; o >>= 1) {
        acc0 += __shfl_down(acc0, o);
        acc1 += __shfl_down(acc1, o);
        acc2 += __shfl_down(acc2, o);
        acc3 += __shfl_down(acc3, o);
    }
    __shared__ float red[4][4];
    if ((t & 63) == 0) {
        const int w = t >> 6;
        red[0][w] = acc0; red[1][w] = acc1; red[2][w] = acc2; red[3][w] = acc3;
    }
    __syncthreads();
    if (t < 4) {
        const int row = r0 + t;
        const float y  = (red[t][0] + red[t][1]) + (red[t][2] + red[t][3]);
        const float dv = d[row];
        const float xn = ALPHA * dv * y + (1.0f - ALPHA) * xin[row];
        xout[row] = xn;
        zout[row] = (unsigned short)f2bf(dv * xn);
    }
}

// ---- Fallback step reading f32 adj + f32 z ----
__global__ __launch_bounds__(256) void k_step_f32(
        const float* __restrict__ adj, const float* __restrict__ d,
        const float* __restrict__ xin, const float* __restrict__ zin,
        float* __restrict__ xout, float* __restrict__ zout) {
    const int row = blockIdx.x;
    const int t   = threadIdx.x;
    const float* arow = adj + (size_t)row * NN;
    float acc = 0.0f;
#pragma unroll
    for (int c = 0; c < 8; ++c) {
        const int j = c * 1024 + t * 4;
        float4 a = *(const float4*)(arow + j);
        float4 z = *(const float4*)(zin + j);
        acc = fmaf(a.x, z.x, acc); acc = fmaf(a.y, z.y, acc);
        acc = fmaf(a.z, z.z, acc); acc = fmaf(a.w, z.w, acc);
    }
#pragma unroll
    for (int o = 32; o > 0; o >>= 1) acc += __shfl_down(acc, o);
    __shared__ float red[4];
    if ((t & 63) == 0) red[t >> 6] = acc;
    __syncthreads();
    if (t == 0) {
        const float y  = (red[0] + red[1]) + (red[2] + red[3]);
        const float dv = d[row];
        const float xn = ALPHA * dv * y + (1.0f - ALPHA) * xin[row];
        xout[row] = xn;
        zout[row] = dv * xn;
    }
}

// ---- updated_adj = M * adj (fallback only) ----
__global__ __launch_bounds__(256) void k_mul(
        const float* __restrict__ adj, const float* __restrict__ M,
        float* __restrict__ out) {
    size_t i = ((size_t)blockIdx.x * blockDim.x + threadIdx.x) * 4;
    const size_t stride = (size_t)gridDim.x * blockDim.x * 4;
    const size_t total = (size_t)NN * NN;
    for (; i < total; i += stride) {
        float4 a = *(const float4*)(adj + i);
        float4 m = *(const float4*)(M + i);
        float4 r;
        r.x = a.x * m.x; r.y = a.y * m.y; r.z = a.z * m.z; r.w = a.w * m.w;
        *(float4*)(out + i) = r;
    }
}

// ---- loss = -(sum pos*log(1-neg+eps)) / sum(pos), 1024 threads (fallback) ----
__global__ __launch_bounds__(1024) void k_loss(
        const float* __restrict__ pos, const float* __restrict__ xfin,
        float* __restrict__ out) {
    const int t = threadIdx.x;
    float sn = 0.0f, sd = 0.0f;
#pragma unroll
    for (int c = 0; c < 8; ++c) {
        const int i4 = c * 1024 + t;
        float4 p = *(const float4*)(pos  + i4 * 4);
        float4 x = *(const float4*)(xfin + i4 * 4);
        sn += p.x * logf(1.0f - x.x + EPSV);
        sn += p.y * logf(1.0f - x.y + EPSV);
        sn += p.z * logf(1.0f - x.z + EPSV);
        sn += p.w * logf(1.0f - x.w + EPSV);
        sd += (p.x + p.y) + (p.z + p.w);
    }
#pragma unroll
    for (int o = 32; o > 0; o >>= 1) {
        sn += __shfl_down(sn, o);
        sd += __shfl_down(sd, o);
    }
    __shared__ float rn[16], rd[16];
    if ((t & 63) == 0) { rn[t >> 6] = sn; rd[t >> 6] = sd; }
    __syncthreads();
    if (t == 0) {
        float n = 0.0f, dd = 0.0f;
#pragma unroll
        for (int k = 0; k < 16; ++k) { n += rn[k]; dd += rd[k]; }
        out[0] = -n / dd;
    }
}

extern "C" void kernel_launch(void* const* d_in, const int* in_sizes, int n_in,
                              void* d_out, int out_size, void* d_ws, size_t ws_size,
                              hipStream_t stream) {
    const float* adj = (const float*)d_in[0];
    const float* pos = (const float*)d_in[1];
    const float* M   = (const float*)d_in[2];
    float* out = (float*)d_out;

    char* ws = (char*)d_ws;
    float* d_vec  = (float*)(ws + 0);
    float* rowsum = (float*)(ws + 32768);
    float* x_a    = (float*)(ws + 65536);
    float* x_b    = (float*)(ws + 98304);
    unsigned short* zb_a = (unsigned short*)(ws + 131072);
    unsigned short* zb_b = (unsigned short*)(ws + 163840);
    float* zf_a   = (float*)(ws + 196608);
    float* zf_b   = (float*)(ws + 229376);
    unsigned char* a8 = (unsigned char*)(ws + 262144);

    const size_t need_fp8 = 262144 + (size_t)NN * NN;
    const bool use_fp8 = (ws_size >= need_fp8);

    // One-time host-side check: can k_coop's 1024 blocks be co-resident?
    static int s_coop = -1;
    if (s_coop < 0) {
        int nb = 0, ncu = 0;
        hipError_t e1 = hipOccupancyMaxActiveBlocksPerMultiprocessor(&nb, k_coop, 256, 0);
        hipError_t e2 = hipDeviceGetAttribute(&ncu, hipDeviceAttributeMultiprocessorCount, 0);
        s_coop = (e1 == hipSuccess && e2 == hipSuccess && nb * ncu >= 1024) ? 1 : 0;
    }

    if (use_fp8) {
        k_fused_prep<<<NN, 256, 0, stream>>>(adj, M, out, a8, rowsum);
    } else {
        k_rowsum<<<NN, 256, 0, stream>>>(adj, rowsum);
    }

    bool coop_done = false;
    if (use_fp8 && s_coop == 1) {
        float* lossp = out + (size_t)NN * NN;
        void* args[9] = { (void*)&a8, (void*)&rowsum, (void*)&pos, (void*)&d_vec,
                          (void*)&x_a, (void*)&x_b, (void*)&zb_a, (void*)&zb_b,
                          (void*)&lossp };
        if (hipLaunchCooperativeKernel((const void*)k_coop, dim3(1024), dim3(256),
                                       args, 0, stream) == hipSuccess) {
            coop_done = true;
        }
    }

    if (!coop_done) {
        k_init<<<NN / 256, 256, 0, stream>>>(rowsum, pos, d_vec, x_a, zb_a, zf_a);
        float* xi = x_a; float* xo = x_b;
        unsigned short* zbi = zb_a; unsigned short* zbo = zb_b;
        float* zfi = zf_a; float* zfo = zf_b;
        for (int s = 0; s < STEPS; ++s) {
            if (use_fp8) {
                k_step_fp8<<<NN / 4, 256, 0, stream>>>(a8, d_vec, xi, zbi, xo, zbo);
                unsigned short* tz = zbi; zbi = zbo; zbo = tz;
            } else {
                k_step_f32<<<NN, 256, 0, stream>>>(adj, d_vec, xi, zfi, xo, zfo);
                float* tz = zfi; zfi = zfo; zfo = tz;
            }
            float* t = xi; xi = xo; xo = t;
        }
        if (!use_fp8) {
            k_mul<<<2048, 256, 0, stream>>>(adj, M, out);
        }
        k_loss<<<1, 1024, 0, stream>>>(pos, xi, out + (size_t)NN * NN);
    }
}

// Round 2
// 261.527 us; speedup vs baseline: 1.0043x; 1.0043x over previous
//
#include <hip/hip_runtime.h>
#include <hip/hip_bf16.h>

#define NN 8192
constexpr int   STEPS = 10;
constexpr float ALPHA = 0.5f;
constexpr float EPSV  = 1e-10f;

typedef float f32x2 __attribute__((ext_vector_type(2)));
typedef float f32x4 __attribute__((ext_vector_type(4)));

static __device__ __forceinline__ unsigned int f2bf(float f) {
    unsigned int u = __float_as_uint(f);
    return (u + 0x7FFFu + ((u >> 16) & 1u)) >> 16;
}
static __device__ __forceinline__ float bf2f(unsigned int h) {
    return __uint_as_float(h << 16);
}

// ---- Fused: updated_adj = M*adj (nt), adj->fp8 copy, rowsum. One row/block ----
// Near fabric-roofline (5.7 TB/s incl. L3-served M) — unchanged.
__global__ __launch_bounds__(256) void k_fused_prep(
        const float* __restrict__ adj, const float* __restrict__ M,
        float* __restrict__ out, unsigned char* __restrict__ a8,
        float* __restrict__ rowsum) {
    const int row = blockIdx.x;
    const int t   = threadIdx.x;
    const float* arow = adj + (size_t)row * NN;
    const float* mrow = M   + (size_t)row * NN;
    float*       orow = out + (size_t)row * NN;
    unsigned char* brow = a8 + (size_t)row * NN;
    float acc = 0.0f;
#pragma unroll
    for (int g = 0; g < 2; ++g) {
        f32x4 v[4], m[4];
#pragma unroll
        for (int k = 0; k < 4; ++k) {
            const int j = (g * 4 + k) * 1024 + t * 4;
            v[k] = __builtin_nontemporal_load((const f32x4*)(arow + j));
        }
#pragma unroll
        for (int k = 0; k < 4; ++k) {
            const int j = (g * 4 + k) * 1024 + t * 4;
            m[k] = __builtin_nontemporal_load((const f32x4*)(mrow + j));
        }
#pragma unroll
        for (int k = 0; k < 4; ++k) {
            const int j = (g * 4 + k) * 1024 + t * 4;
            f32x4 r = v[k] * m[k];
            __builtin_nontemporal_store(r, (f32x4*)(orow + j));
            acc += (v[k].x + v[k].y) + (v[k].z + v[k].w);
            int p = __builtin_amdgcn_cvt_pk_fp8_f32(v[k].x, v[k].y, 0, false);
            p     = __builtin_amdgcn_cvt_pk_fp8_f32(v[k].z, v[k].w, p, true);
            *(unsigned int*)(brow + j) = (unsigned int)p;
        }
    }
#pragma unroll
    for (int o = 32; o > 0; o >>= 1) acc += __shfl_down(acc, o);
    __shared__ float red[4];
    if ((t & 63) == 0) red[t >> 6] = acc;
    __syncthreads();
    if (t == 0) rowsum[row] = (red[0] + red[1]) + (red[2] + red[3]);
}

// ================= Persistent chain (single regular launch) =================
// 256 blocks x 256 threads, 1 block/CU, 32 rows/block. Each thread keeps its
// 32B slice of all 32 rows in REGISTERS (256 VGPRs of A; budget 512 via
// __launch_bounds__(256,1)) -> a8 read from memory ONCE; steps 2..10 are pure
// VALU + a 16KB z exchange. Flag-based global barrier (no counter contention),
// flags zeroed by a captured hipMemsetAsync every launch.
#define CBLK  256
#define CROWS 32

static __device__ __forceinline__ void gbar(unsigned int* flags, unsigned int phase) {
    __syncthreads();   // drains vmcnt: all this block's z stores are at LLC
    if (threadIdx.x == 0)
        __hip_atomic_store(&flags[blockIdx.x], phase, __ATOMIC_RELEASE,
                           __HIP_MEMORY_SCOPE_AGENT);
    while (__hip_atomic_load(&flags[threadIdx.x], __ATOMIC_ACQUIRE,
                             __HIP_MEMORY_SCOPE_AGENT) < phase)
        __builtin_amdgcn_s_sleep(1);
    __syncthreads();
}

#define FMA_WORD(w, base)                                             \
    { f32x2 lo = __builtin_amdgcn_cvt_pk_f32_fp8((int)(w), false);    \
      f32x2 hi = __builtin_amdgcn_cvt_pk_f32_fp8((int)(w), true);     \
      a0 = fmaf(lo[0], zf[(base) + 0], a0);                           \
      a1 = fmaf(lo[1], zf[(base) + 1], a1);                           \
      a0 = fmaf(hi[0], zf[(base) + 2], a0);                           \
      a1 = fmaf(hi[1], zf[(base) + 3], a1); }

__global__ __launch_bounds__(256, 1) void k_chain(
        const unsigned char* __restrict__ a8, const float* __restrict__ rowsum,
        const float* __restrict__ pos,
        unsigned int* __restrict__ z_a, unsigned int* __restrict__ z_b,
        unsigned int* __restrict__ flags, float* __restrict__ accs,
        float* __restrict__ loss_out) {
    const int t  = threadIdx.x;
    const int b  = blockIdx.x;
    const int r0 = b * CROWS;
    __shared__ float xloc[CROWS], dloc[CROWS], ploc[CROWS];
    __shared__ unsigned short zs[CROWS];
    __shared__ float red[CROWS][4];

    // ---- init: this block's 32 rows ----
    if (t < CROWS) {
        const int row = r0 + t;
        const float dv = rsqrtf(rowsum[row]);
        const float pv = pos[row];
        const float xv = 1.0f - pv;
        dloc[t] = dv; ploc[t] = pv; xloc[t] = xv;
        zs[t] = (unsigned short)f2bf(dv * xv);
    }
    __syncthreads();
    if (t < CROWS / 2) {
        unsigned int w = (unsigned)zs[2 * t] | ((unsigned)zs[2 * t + 1] << 16);
        __hip_atomic_store(&z_a[r0 / 2 + t], w, __ATOMIC_RELAXED,
                           __HIP_MEMORY_SCOPE_AGENT);
    }
    gbar(flags, 1u);

    // ---- stage this block's a8 rows into registers (one pass over a8) ----
    const int j = t * 32;           // byte/elem offset within a row
    uint4 pa[CROWS][2];
#pragma unroll
    for (int r = 0; r < CROWS; ++r) {
        const unsigned char* arow = a8 + (size_t)(r0 + r) * NN + j;
        pa[r][0] = *(const uint4*)(arow);
        pa[r][1] = *(const uint4*)(arow + 16);
    }

    const unsigned int* zi = z_a;
    unsigned int*       zo = z_b;
#pragma unroll 1
    for (int s = 0; s < STEPS; ++s) {
        // z slice: 16 coherent u32 loads -> 32 f32
        float zf[32];
#pragma unroll
        for (int k = 0; k < 16; ++k) {
            unsigned int q = __hip_atomic_load(&zi[(j >> 1) + k], __ATOMIC_RELAXED,
                                               __HIP_MEMORY_SCOPE_AGENT);
            zf[2 * k]     = bf2f(q & 0xFFFFu);
            zf[2 * k + 1] = bf2f(q >> 16);
        }
        float acc[CROWS];
#pragma unroll
        for (int r = 0; r < CROWS; ++r) {
            float a0 = 0.0f, a1 = 0.0f;
            FMA_WORD(pa[r][0].x,  0) FMA_WORD(pa[r][0].y,  4)
            FMA_WORD(pa[r][0].z,  8) FMA_WORD(pa[r][0].w, 12)
            FMA_WORD(pa[r][1].x, 16) FMA_WORD(pa[r][1].y, 20)
            FMA_WORD(pa[r][1].z, 24) FMA_WORD(pa[r][1].w, 28)
            acc[r] = a0 + a1;
        }
#pragma unroll
        for (int r = 0; r < CROWS; ++r) {
#pragma unroll
            for (int o = 32; o > 0; o >>= 1) acc[r] += __shfl_down(acc[r], o);
        }
        if ((t & 63) == 0) {
            const int w = t >> 6;
#pragma unroll
            for (int r = 0; r < CROWS; ++r) red[r][w] = acc[r];
        }
        __syncthreads();
        if (t < CROWS) {
            const float y  = (red[t][0] + red[t][1]) + (red[t][2] + red[t][3]);
            const float dv = dloc[t];
            const float xn = ALPHA * dv * y + (1.0f - ALPHA) * xloc[t];
            xloc[t] = xn;
            zs[t] = (unsigned short)f2bf(dv * xn);
        }
        __syncthreads();
        if (s < STEPS - 1) {
            if (t < CROWS / 2) {
                unsigned int w = (unsigned)zs[2 * t] | ((unsigned)zs[2 * t + 1] << 16);
                __hip_atomic_store(&zo[r0 / 2 + t], w, __ATOMIC_RELAXED,
                                   __HIP_MEMORY_SCOPE_AGENT);
            }
            gbar(flags, (unsigned)(2 + s));
            const unsigned int* tz = zi; zi = zo; zo = (unsigned int*)tz;
        }
    }

    // ---- loss: block partial over its 32 rows, atomic combine, last block divides ----
    if (t < CROWS) {
        const float xn = xloc[t];
        red[t][0] = ploc[t] * logf(1.0f - xn + EPSV);
        red[t][1] = ploc[t];
    }
    __syncthreads();
    if (t == 0) {
        float n = 0.0f, dd = 0.0f;
#pragma unroll
        for (int r = 0; r < CROWS; ++r) { n += red[r][0]; dd += red[r][1]; }
        atomicAdd(&accs[0], n);
        atomicAdd(&accs[1], dd);
        unsigned int tk = __hip_atomic_fetch_add((unsigned int*)&accs[2], 1u,
                                                 __ATOMIC_ACQ_REL,
                                                 __HIP_MEMORY_SCOPE_AGENT);
        if (tk == CBLK - 1) {
            float sn = __hip_atomic_load(&accs[0], __ATOMIC_RELAXED,
                                         __HIP_MEMORY_SCOPE_AGENT);
            float sd = __hip_atomic_load(&accs[1], __ATOMIC_RELAXED,
                                         __HIP_MEMORY_SCOPE_AGENT);
            loss_out[0] = -sn / sd;
        }
    }
}

// ===================== Fallback path (proven, unchanged) =====================
__global__ __launch_bounds__(256) void k_rowsum(
        const float* __restrict__ adj, float* __restrict__ rowsum) {
    const int row = blockIdx.x;
    const int t   = threadIdx.x;
    const float* arow = adj + (size_t)row * NN;
    float acc = 0.0f;
#pragma unroll
    for (int c = 0; c < 8; ++c) {
        const int j = c * 1024 + t * 4;
        float4 v = *(const float4*)(arow + j);
        acc += (v.x + v.y) + (v.z + v.w);
    }
#pragma unroll
    for (int o = 32; o > 0; o >>= 1) acc += __shfl_down(acc, o);
    __shared__ float red[4];
    if ((t & 63) == 0) red[t >> 6] = acc;
    __syncthreads();
    if (t == 0) rowsum[row] = (red[0] + red[1]) + (red[2] + red[3]);
}

__global__ __launch_bounds__(256) void k_init(
        const float* __restrict__ rowsum, const float* __restrict__ pos,
        float* __restrict__ d, float* __restrict__ x,
        unsigned short* __restrict__ zbf, float* __restrict__ zf) {
    const int i = blockIdx.x * 256 + threadIdx.x;
    const float dv = rsqrtf(rowsum[i]);
    const float xv = 1.0f - pos[i];
    const float zv = dv * xv;
    d[i] = dv;
    x[i] = xv;
    zbf[i] = (unsigned short)f2bf(zv);
    zf[i] = zv;
}

__global__ __launch_bounds__(256) void k_step_fp8(
        const unsigned char* __restrict__ a8, const float* __restrict__ d,
        const float* __restrict__ xin, const unsigned short* __restrict__ zin,
        float* __restrict__ xout, unsigned short* __restrict__ zout) {
    const int r0 = blockIdx.x * 4;
    const int t  = threadIdx.x;
    const int j  = t * 32;

    uint4 pa[4][2];
#pragma unroll
    for (int r = 0; r < 4; ++r) {
        const unsigned char* arow = a8 + (size_t)(r0 + r) * NN + j;
        pa[r][0] = *(const uint4*)(arow);
        pa[r][1] = *(const uint4*)(arow + 16);
    }
    uint4 zp[4];
#pragma unroll
    for (int k = 0; k < 4; ++k)
        zp[k] = *(const uint4*)(zin + j + 8 * k);

    float acc0 = 0.0f, acc1 = 0.0f, acc2 = 0.0f, acc3 = 0.0f;
#pragma unroll
    for (int h = 0; h < 2; ++h) {
        float zf[16];
#pragma unroll
        for (int k = 0; k < 2; ++k) {
            uint4 q = zp[2 * h + k];
            zf[k * 8 + 0] = bf2f(q.x & 0xFFFFu); zf[k * 8 + 1] = bf2f(q.x >> 16);
            zf[k * 8 + 2] = bf2f(q.y & 0xFFFFu); zf[k * 8 + 3] = bf2f(q.y >> 16);
            zf[k * 8 + 4] = bf2f(q.z & 0xFFFFu); zf[k * 8 + 5] = bf2f(q.z >> 16);
            zf[k * 8 + 6] = bf2f(q.w & 0xFFFFu); zf[k * 8 + 7] = bf2f(q.w >> 16);
        }
#pragma unroll
        for (int r = 0; r < 4; ++r) {
            const uint4 p = pa[r][h];
            unsigned int w[4] = {p.x, p.y, p.z, p.w};
            float a = 0.0f;
#pragma unroll
            for (int wi = 0; wi < 4; ++wi) {
                f32x2 lo = __builtin_amdgcn_cvt_pk_f32_fp8((int)w[wi], false);
                f32x2 hi = __builtin_amdgcn_cvt_pk_f32_fp8((int)w[wi], true);
                a = fmaf(lo[0], zf[wi * 4 + 0], a);
                a = fmaf(lo[1], zf[wi * 4 + 1], a);
                a = fmaf(hi[0], zf[wi * 4 + 2], a);
                a = fmaf(hi[1], zf[wi * 4 + 3], a);
            }
            if (r == 0) acc0 += a; else if (r == 1) acc1 += a;
            else if (r == 2) acc2 += a; else acc3 += a;
        }
    }
#pragma unroll
    for (int o = 32; o > 0; o >>= 1) {
        acc0 += __shfl_down(acc0, o);
        acc1 += __shfl_down(acc1, o);
        acc2 += __shfl_down(acc2, o);
        acc3 += __shfl_down(acc3, o);
    }
    __shared__ float red[4][4];
    if ((t & 63) == 0) {
        const int w = t >> 6;
        red[0][w] = acc0; red[1][w] = acc1; red[2][w] = acc2; red[3][w] = acc3;
    }
    __syncthreads();
    if (t < 4) {
        const int row = r0 + t;
        const float y  = (red[t][0] + red[t][1]) + (red[t][2] + red[t][3]);
        const float dv = d[row];
        const float xn = ALPHA * dv * y + (1.0f - ALPHA) * xin[row];
        xout[row] = xn;
        zout[row] = (unsigned short)f2bf(dv * xn);
    }
}

__global__ __launch_bounds__(256) void k_step_f32(
        const float* __restrict__ adj, const float* __restrict__ d,
        const float* __restrict__ xin, const float* __restrict__ zin,
        float* __restrict__ xout, float* __restrict__ zout) {
    const int row = blockIdx.x;
    const int t   = threadIdx.x;
    const float* arow = adj + (size_t)row * NN;
    float acc = 0.0f;
#pragma unroll
    for (int c = 0; c < 8; ++c) {
        const int j = c * 1024 + t * 4;
        float4 a = *(const float4*)(arow + j);
        float4 z = *(const float4*)(zin + j);
        acc = fmaf(a.x, z.x, acc); acc = fmaf(a.y, z.y, acc);
        acc = fmaf(a.z, z.z, acc); acc = fmaf(a.w, z.w, acc);
    }
#pragma unroll
    for (int o = 32; o > 0; o >>= 1) acc += __shfl_down(acc, o);
    __shared__ float red[4];
    if ((t & 63) == 0) red[t >> 6] = acc;
    __syncthreads();
    if (t == 0) {
        const float y  = (red[0] + red[1]) + (red[2] + red[3]);
        const float dv = d[row];
        const float xn = ALPHA * dv * y + (1.0f - ALPHA) * xin[row];
        xout[row] = xn;
        zout[row] = dv * xn;
    }
}

__global__ __launch_bounds__(256) void k_mul(
        const float* __restrict__ adj, const float* __restrict__ M,
        float* __restrict__ out) {
    size_t i = ((size_t)blockIdx.x * blockDim.x + threadIdx.x) * 4;
    const size_t stride = (size_t)gridDim.x * blockDim.x * 4;
    const size_t total = (size_t)NN * NN;
    for (; i < total; i += stride) {
        float4 a = *(const float4*)(adj + i);
        float4 m = *(const float4*)(M + i);
        float4 r;
        r.x = a.x * m.x; r.y = a.y * m.y; r.z = a.z * m.z; r.w = a.w * m.w;
        *(float4*)(out + i) = r;
    }
}

__global__ __launch_bounds__(1024) void k_loss(
        const float* __restrict__ pos, const float* __restrict__ xfin,
        float* __restrict__ out) {
    const int t = threadIdx.x;
    float sn = 0.0f, sd = 0.0f;
#pragma unroll
    for (int c = 0; c < 8; ++c) {
        const int i4 = c * 1024 + t;
        float4 p = *(const float4*)(pos  + i4 * 4);
        float4 x = *(const float4*)(xfin + i4 * 4);
        sn += p.x * logf(1.0f - x.x + EPSV);
        sn += p.y * logf(1.0f - x.y + EPSV);
        sn += p.z * logf(1.0f - x.z + EPSV);
        sn += p.w * logf(1.0f - x.w + EPSV);
        sd += (p.x + p.y) + (p.z + p.w);
    }
#pragma unroll
    for (int o = 32; o > 0; o >>= 1) {
        sn += __shfl_down(sn, o);
        sd += __shfl_down(sd, o);
    }
    __shared__ float rn[16], rd[16];
    if ((t & 63) == 0) { rn[t >> 6] = sn; rd[t >> 6] = sd; }
    __syncthreads();
    if (t == 0) {
        float n = 0.0f, dd = 0.0f;
#pragma unroll
        for (int k = 0; k < 16; ++k) { n += rn[k]; dd += rd[k]; }
        out[0] = -n / dd;
    }
}

extern "C" void kernel_launch(void* const* d_in, const int* in_sizes, int n_in,
                              void* d_out, int out_size, void* d_ws, size_t ws_size,
                              hipStream_t stream) {
    const float* adj = (const float*)d_in[0];
    const float* pos = (const float*)d_in[1];
    const float* M   = (const float*)d_in[2];
    float* out = (float*)d_out;

    char* ws = (char*)d_ws;
    float* d_vec  = (float*)(ws + 0);
    float* rowsum = (float*)(ws + 32768);
    float* x_a    = (float*)(ws + 65536);
    float* x_b    = (float*)(ws + 98304);
    unsigned short* zb_a = (unsigned short*)(ws + 131072);
    unsigned short* zb_b = (unsigned short*)(ws + 163840);
    unsigned int* flags  = (unsigned int*)(ws + 196608);   // 1 KB flags
    float*        accs   = (float*)(ws + 196608 + 4096);   // sn, sd, ticket
    float* zf_a   = (float*)(ws + 196608);                 // fallback reuse (exclusive paths)
    float* zf_b   = (float*)(ws + 229376);
    unsigned char* a8 = (unsigned char*)(ws + 262144);

    const size_t need_fp8 = 262144 + (size_t)NN * NN;
    const bool use_fp8 = (ws_size >= need_fp8);

    // One-time host-side check (pure query, capture-safe): k_chain residency.
    static int s_chain = -1;
    if (s_chain < 0) {
        int nb = 0, ncu = 0;
        hipError_t e1 = hipOccupancyMaxActiveBlocksPerMultiprocessor(&nb, k_chain, 256, 0);
        hipError_t e2 = hipDeviceGetAttribute(&ncu, hipDeviceAttributeMultiprocessorCount, 0);
        s_chain = (e1 == hipSuccess && e2 == hipSuccess && nb >= 1 && nb * ncu >= CBLK) ? 1 : 0;
    }

    if (use_fp8) {
        k_fused_prep<<<NN, 256, 0, stream>>>(adj, M, out, a8, rowsum);
    } else {
        k_rowsum<<<NN, 256, 0, stream>>>(adj, rowsum);
    }

    if (use_fp8 && s_chain == 1) {
        // zero barrier flags + loss accumulators every launch (captured node)
        hipMemsetAsync(flags, 0, 4096 + 64, stream);
        k_chain<<<CBLK, 256, 0, stream>>>(a8, rowsum, pos,
                                          (unsigned int*)zb_a, (unsigned int*)zb_b,
                                          flags, accs, out + (size_t)NN * NN);
        return;
    }

    // -------- fallback: proven multi-launch path --------
    k_init<<<NN / 256, 256, 0, stream>>>(rowsum, pos, d_vec, x_a, zb_a, zf_a);
    float* xi = x_a; float* xo = x_b;
    unsigned short* zbi = zb_a; unsigned short* zbo = zb_b;
    float* zfi = zf_a; float* zfo = zf_b;
    for (int s = 0; s < STEPS; ++s) {
        if (use_fp8) {
            k_step_fp8<<<NN / 4, 256, 0, stream>>>(a8, d_vec, xi, zbi, xo, zbo);
            unsigned short* tz = zbi; zbi = zbo; zbo = tz;
        } else {
            k_step_f32<<<NN, 256, 0, stream>>>(adj, d_vec, xi, zfi, xo, zfo);
            float* tz = zfi; zfi = zfo; zfo = tz;
        }
        float* t = xi; xi = xo; xo = t;
    }
    if (!use_fp8) {
        k_mul<<<2048, 256, 0, stream>>>(adj, M, out);
    }
    k_loss<<<1, 1024, 0, stream>>>(pos, xi, out + (size_t)NN * NN);
}

// Round 3
// 260.987 us; speedup vs baseline: 1.0063x; 1.0021x over previous
//
#include <hip/hip_runtime.h>
#include <hip/hip_bf16.h>

#define NN 8192
constexpr int   STEPS = 10;
constexpr float ALPHA = 0.5f;
constexpr float EPSV  = 1e-10f;

typedef float f32x2 __attribute__((ext_vector_type(2)));
typedef float f32x4 __attribute__((ext_vector_type(4)));

static __device__ __forceinline__ unsigned int f2bf(float f) {
    unsigned int u = __float_as_uint(f);
    return (u + 0x7FFFu + ((u >> 16) & 1u)) >> 16;
}
static __device__ __forceinline__ float bf2f(unsigned int h) {
    return __uint_as_float(h << 16);
}

// ---- Fused: updated_adj = M*adj (nt), adj->fp8 copy, rowsum. One row/block ----
// Near fabric-roofline (5.7 TB/s incl. L3-served M) — unchanged.
__global__ __launch_bounds__(256) void k_fused_prep(
        const float* __restrict__ adj, const float* __restrict__ M,
        float* __restrict__ out, unsigned char* __restrict__ a8,
        float* __restrict__ rowsum) {
    const int row = blockIdx.x;
    const int t   = threadIdx.x;
    const float* arow = adj + (size_t)row * NN;
    const float* mrow = M   + (size_t)row * NN;
    float*       orow = out + (size_t)row * NN;
    unsigned char* brow = a8 + (size_t)row * NN;
    float acc = 0.0f;
#pragma unroll
    for (int g = 0; g < 2; ++g) {
        f32x4 v[4], m[4];
#pragma unroll
        for (int k = 0; k < 4; ++k) {
            const int j = (g * 4 + k) * 1024 + t * 4;
            v[k] = __builtin_nontemporal_load((const f32x4*)(arow + j));
        }
#pragma unroll
        for (int k = 0; k < 4; ++k) {
            const int j = (g * 4 + k) * 1024 + t * 4;
            m[k] = __builtin_nontemporal_load((const f32x4*)(mrow + j));
        }
#pragma unroll
        for (int k = 0; k < 4; ++k) {
            const int j = (g * 4 + k) * 1024 + t * 4;
            f32x4 r = v[k] * m[k];
            __builtin_nontemporal_store(r, (f32x4*)(orow + j));
            acc += (v[k].x + v[k].y) + (v[k].z + v[k].w);
            int p = __builtin_amdgcn_cvt_pk_fp8_f32(v[k].x, v[k].y, 0, false);
            p     = __builtin_amdgcn_cvt_pk_fp8_f32(v[k].z, v[k].w, p, true);
            *(unsigned int*)(brow + j) = (unsigned int)p;
        }
    }
#pragma unroll
    for (int o = 32; o > 0; o >>= 1) acc += __shfl_down(acc, o);
    __shared__ float red[4];
    if ((t & 63) == 0) red[t >> 6] = acc;
    __syncthreads();
    if (t == 0) rowsum[row] = (red[0] + red[1]) + (red[2] + red[3]);
}

// ================= Persistent chain (single regular launch) =================
// 256 blocks x 256 threads, 1 block/CU (forced by 132KB LDS). 32 rows/block:
//   16 rows resident in VGPRs (pa[16][2] = 128 regs of data, fits in the
//   256-architected-VGPR limit that round 2 violated), and
//   16 rows resident in LDS (128KB, XOR-swizzled chunks for ~2-way banks).
// a8 is read from HBM ONCE; steps are VALU + ds_read + 16KB z exchange.
#define CBLK  256
#define CROWS 32
#define RREG  16
#define RLDS  16

static __device__ __forceinline__ void gbar(unsigned int* flags, unsigned int phase) {
    __syncthreads();
    if (threadIdx.x == 0)
        __hip_atomic_store(&flags[blockIdx.x], phase, __ATOMIC_RELEASE,
                           __HIP_MEMORY_SCOPE_AGENT);
    while (__hip_atomic_load(&flags[threadIdx.x], __ATOMIC_ACQUIRE,
                             __HIP_MEMORY_SCOPE_AGENT) < phase)
        __builtin_amdgcn_s_sleep(1);
    __syncthreads();
}

// chunk swizzle: 16B chunk c of a row stored at slot c ^ ((c>>3)&7).
// Lanes 0..7 then hit bank-starts {0,8,16,24,4,12,20,28} -> every 8-lane
// group covers all 32 banks -> 2-way aliasing (free, m136).
static __device__ __forceinline__ int lds_off(int r, int c) {
    return r * 8192 + ((c ^ ((c >> 3) & 7)) << 4);
}

// word w = 4 fp8 values; pairs with zf2[m] (vals 0,1) and zf2[m+1] (vals 2,3).
// f32x2 accumulators invite v_pk_fma_f32; a01/a23 rotation gives dep slack.
#define FMA_WORD(w, m)                                                \
    { f32x2 lo = __builtin_amdgcn_cvt_pk_f32_fp8((int)(w), false);    \
      f32x2 hi = __builtin_amdgcn_cvt_pk_f32_fp8((int)(w), true);     \
      a01 += lo * zf2[(m)];                                           \
      a23 += hi * zf2[(m) + 1]; }

#define DOT_ROW(q0, q1, res)                                                        \
    { f32x2 a01 = {0.f, 0.f}, a23 = {0.f, 0.f};                                     \
      FMA_WORD(q0.x, 0)  FMA_WORD(q0.y, 2)  FMA_WORD(q0.z, 4)  FMA_WORD(q0.w, 6)   \
      FMA_WORD(q1.x, 8)  FMA_WORD(q1.y, 10) FMA_WORD(q1.z, 12) FMA_WORD(q1.w, 14)  \
      res = (a01[0] + a01[1]) + (a23[0] + a23[1]); }

__global__ __launch_bounds__(256, 1) void k_chain(
        const unsigned char* __restrict__ a8, const float* __restrict__ rowsum,
        const float* __restrict__ pos,
        unsigned int* __restrict__ z_a, unsigned int* __restrict__ z_b,
        unsigned int* __restrict__ flags, float* __restrict__ accs,
        float* __restrict__ loss_out) {
    const int t  = threadIdx.x;
    const int b  = blockIdx.x;
    const int r0 = b * CROWS;

    __shared__ __align__(16) unsigned char lds_a[RLDS * 8192];   // 128 KB
    __shared__ float xloc[CROWS], dloc[CROWS], ploc[CROWS];
    __shared__ unsigned short zs[CROWS];
    __shared__ float red[CROWS][4];

    // ---- init: this block's 32 rows ----
    if (t < CROWS) {
        const int row = r0 + t;
        const float dv = rsqrtf(rowsum[row]);
        const float pv = pos[row];
        const float xv = 1.0f - pv;
        dloc[t] = dv; ploc[t] = pv; xloc[t] = xv;
        zs[t] = (unsigned short)f2bf(dv * xv);
    }
    __syncthreads();
    if (t < CROWS / 2) {
        unsigned int w = (unsigned)zs[2 * t] | ((unsigned)zs[2 * t + 1] << 16);
        __hip_atomic_store(&z_a[r0 / 2 + t], w, __ATOMIC_RELAXED,
                           __HIP_MEMORY_SCOPE_AGENT);
    }

    // ---- stage A: rows 0..15 into registers, rows 16..31 into LDS ----
    const int j = t * 32;               // byte/elem offset within a row
    uint4 pa[RREG][2];
#pragma unroll
    for (int r = 0; r < RREG; ++r) {
        const unsigned char* arow = a8 + (size_t)(r0 + r) * NN + j;
        pa[r][0] = *(const uint4*)(arow);
        pa[r][1] = *(const uint4*)(arow + 16);
    }
#pragma unroll
    for (int g = 0; g < 4; ++g) {
        uint4 v0[4], v1[4];
#pragma unroll
        for (int rr = 0; rr < 4; ++rr) {
            const unsigned char* arow =
                a8 + (size_t)(r0 + RREG + g * 4 + rr) * NN + j;
            v0[rr] = *(const uint4*)(arow);
            v1[rr] = *(const uint4*)(arow + 16);
        }
#pragma unroll
        for (int rr = 0; rr < 4; ++rr) {
            const int lr = g * 4 + rr;
            *(uint4*)&lds_a[lds_off(lr, 2 * t)]     = v0[rr];
            *(uint4*)&lds_a[lds_off(lr, 2 * t + 1)] = v1[rr];
        }
    }
    gbar(flags, 1u);    // also covers the ds_writes via its __syncthreads

    const unsigned int* zi = z_a;
    unsigned int*       zo = z_b;
#pragma unroll 1
    for (int s = 0; s < STEPS; ++s) {
        // z slice: 4 coalesced uint4 loads (fresh after gbar's acquire)
        f32x2 zf2[16];
        {
            const uint4* zv = (const uint4*)(zi + t * 16);
            uint4 zq[4];
#pragma unroll
            for (int k = 0; k < 4; ++k) zq[k] = zv[k];
#pragma unroll
            for (int k = 0; k < 4; ++k) {
                const unsigned int ww[4] = {zq[k].x, zq[k].y, zq[k].z, zq[k].w};
#pragma unroll
                for (int m = 0; m < 4; ++m) {
                    f32x2 p;
                    p[0] = bf2f(ww[m] & 0xFFFFu);
                    p[1] = bf2f(ww[m] >> 16);
                    zf2[k * 4 + m] = p;
                }
            }
        }
        // ---- phase A: 16 register-resident rows ----
        float accA[RREG];
#pragma unroll
        for (int r = 0; r < RREG; ++r) {
            DOT_ROW(pa[r][0], pa[r][1], accA[r]);
        }
#pragma unroll
        for (int r = 0; r < RREG; ++r) {
#pragma unroll
            for (int o = 32; o > 0; o >>= 1) accA[r] += __shfl_down(accA[r], o);
        }
        if ((t & 63) == 0) {
            const int w = t >> 6;
#pragma unroll
            for (int r = 0; r < RREG; ++r) red[r][w] = accA[r];
        }
        // ---- phase B: 16 LDS-resident rows ----
        float accB[RLDS];
#pragma unroll
        for (int r = 0; r < RLDS; ++r) {
            const uint4 q0 = *(const uint4*)&lds_a[lds_off(r, 2 * t)];
            const uint4 q1 = *(const uint4*)&lds_a[lds_off(r, 2 * t + 1)];
            DOT_ROW(q0, q1, accB[r]);
            if ((r & 3) == 3) __builtin_amdgcn_sched_barrier(0);  // cap ds_read hoisting
        }
#pragma unroll
        for (int r = 0; r < RLDS; ++r) {
#pragma unroll
            for (int o = 32; o > 0; o >>= 1) accB[r] += __shfl_down(accB[r], o);
        }
        if ((t & 63) == 0) {
            const int w = t >> 6;
#pragma unroll
            for (int r = 0; r < RLDS; ++r) red[RREG + r][w] = accB[r];
        }
        __syncthreads();
        if (t < CROWS) {
            const float y  = (red[t][0] + red[t][1]) + (red[t][2] + red[t][3]);
            const float dv = dloc[t];
            const float xn = ALPHA * dv * y + (1.0f - ALPHA) * xloc[t];
            xloc[t] = xn;
            zs[t] = (unsigned short)f2bf(dv * xn);
        }
        __syncthreads();
        if (s < STEPS - 1) {
            if (t < CROWS / 2) {
                unsigned int w = (unsigned)zs[2 * t] | ((unsigned)zs[2 * t + 1] << 16);
                __hip_atomic_store(&zo[r0 / 2 + t], w, __ATOMIC_RELAXED,
                                   __HIP_MEMORY_SCOPE_AGENT);
            }
            gbar(flags, (unsigned)(2 + s));
            const unsigned int* tz = zi; zi = zo; zo = (unsigned int*)tz;
        }
    }

    // ---- loss: block partial, atomic combine, last block divides ----
    if (t < CROWS) {
        const float xn = xloc[t];
        red[t][0] = ploc[t] * logf(1.0f - xn + EPSV);
        red[t][1] = ploc[t];
    }
    __syncthreads();
    if (t == 0) {
        float n = 0.0f, dd = 0.0f;
#pragma unroll
        for (int r = 0; r < CROWS; ++r) { n += red[r][0]; dd += red[r][1]; }
        atomicAdd(&accs[0], n);
        atomicAdd(&accs[1], dd);
        unsigned int tk = __hip_atomic_fetch_add((unsigned int*)&accs[2], 1u,
                                                 __ATOMIC_ACQ_REL,
                                                 __HIP_MEMORY_SCOPE_AGENT);
        if (tk == CBLK - 1) {
            float sn = __hip_atomic_load(&accs[0], __ATOMIC_RELAXED,
                                         __HIP_MEMORY_SCOPE_AGENT);
            float sd = __hip_atomic_load(&accs[1], __ATOMIC_RELAXED,
                                         __HIP_MEMORY_SCOPE_AGENT);
            loss_out[0] = -sn / sd;
        }
    }
}

// ===================== Fallback path (proven, unchanged) =====================
__global__ __launch_bounds__(256) void k_rowsum(
        const float* __restrict__ adj, float* __restrict__ rowsum) {
    const int row = blockIdx.x;
    const int t   = threadIdx.x;
    const float* arow = adj + (size_t)row * NN;
    float acc = 0.0f;
#pragma unroll
    for (int c = 0; c < 8; ++c) {
        const int j = c * 1024 + t * 4;
        float4 v = *(const float4*)(arow + j);
        acc += (v.x + v.y) + (v.z + v.w);
    }
#pragma unroll
    for (int o = 32; o > 0; o >>= 1) acc += __shfl_down(acc, o);
    __shared__ float red[4];
    if ((t & 63) == 0) red[t >> 6] = acc;
    __syncthreads();
    if (t == 0) rowsum[row] = (red[0] + red[1]) + (red[2] + red[3]);
}

__global__ __launch_bounds__(256) void k_init(
        const float* __restrict__ rowsum, const float* __restrict__ pos,
        float* __restrict__ d, float* __restrict__ x,
        unsigned short* __restrict__ zbf, float* __restrict__ zf) {
    const int i = blockIdx.x * 256 + threadIdx.x;
    const float dv = rsqrtf(rowsum[i]);
    const float xv = 1.0f - pos[i];
    const float zv = dv * xv;
    d[i] = dv;
    x[i] = xv;
    zbf[i] = (unsigned short)f2bf(zv);
    zf[i] = zv;
}

__global__ __launch_bounds__(256) void k_step_fp8(
        const unsigned char* __restrict__ a8, const float* __restrict__ d,
        const float* __restrict__ xin, const unsigned short* __restrict__ zin,
        float* __restrict__ xout, unsigned short* __restrict__ zout) {
    const int r0 = blockIdx.x * 4;
    const int t  = threadIdx.x;
    const int j  = t * 32;

    uint4 pa[4][2];
#pragma unroll
    for (int r = 0; r < 4; ++r) {
        const unsigned char* arow = a8 + (size_t)(r0 + r) * NN + j;
        pa[r][0] = *(const uint4*)(arow);
        pa[r][1] = *(const uint4*)(arow + 16);
    }
    uint4 zp[4];
#pragma unroll
    for (int k = 0; k < 4; ++k)
        zp[k] = *(const uint4*)(zin + j + 8 * k);

    float acc0 = 0.0f, acc1 = 0.0f, acc2 = 0.0f, acc3 = 0.0f;
#pragma unroll
    for (int h = 0; h < 2; ++h) {
        float zf[16];
#pragma unroll
        for (int k = 0; k < 2; ++k) {
            uint4 q = zp[2 * h + k];
            zf[k * 8 + 0] = bf2f(q.x & 0xFFFFu); zf[k * 8 + 1] = bf2f(q.x >> 16);
            zf[k * 8 + 2] = bf2f(q.y & 0xFFFFu); zf[k * 8 + 3] = bf2f(q.y >> 16);
            zf[k * 8 + 4] = bf2f(q.z & 0xFFFFu); zf[k * 8 + 5] = bf2f(q.z >> 16);
            zf[k * 8 + 6] = bf2f(q.w & 0xFFFFu); zf[k * 8 + 7] = bf2f(q.w >> 16);
        }
#pragma unroll
        for (int r = 0; r < 4; ++r) {
            const uint4 p = pa[r][h];
            unsigned int w[4] = {p.x, p.y, p.z, p.w};
            float a = 0.0f;
#pragma unroll
            for (int wi = 0; wi < 4; ++wi) {
                f32x2 lo = __builtin_amdgcn_cvt_pk_f32_fp8((int)w[wi], false);
                f32x2 hi = __builtin_amdgcn_cvt_pk_f32_fp8((int)w[wi], true);
                a = fmaf(lo[0], zf[wi * 4 + 0], a);
                a = fmaf(lo[1], zf[wi * 4 + 1], a);
                a = fmaf(hi[0], zf[wi * 4 + 2], a);
                a = fmaf(hi[1], zf[wi * 4 + 3], a);
            }
            if (r == 0) acc0 += a; else if (r == 1) acc1 += a;
            else if (r == 2) acc2 += a; else acc3 += a;
        }
    }
#pragma unroll
    for (int o = 32; o > 0; o >>= 1) {
        acc0 += __shfl_down(acc0, o);
        acc1 += __shfl_down(acc1, o);
        acc2 += __shfl_down(acc2, o);
        acc3 += __shfl_down(acc3, o);
    }
    __shared__ float red[4][4];
    if ((t & 63) == 0) {
        const int w = t >> 6;
        red[0][w] = acc0; red[1][w] = acc1; red[2][w] = acc2; red[3][w] = acc3;
    }
    __syncthreads();
    if (t < 4) {
        const int row = r0 + t;
        const float y  = (red[t][0] + red[t][1]) + (red[t][2] + red[t][3]);
        const float dv = d[row];
        const float xn = ALPHA * dv * y + (1.0f - ALPHA) * xin[row];
        xout[row] = xn;
        zout[row] = (unsigned short)f2bf(dv * xn);
    }
}

__global__ __launch_bounds__(256) void k_step_f32(
        const float* __restrict__ adj, const float* __restrict__ d,
        const float* __restrict__ xin, const float* __restrict__ zin,
        float* __restrict__ xout, float* __restrict__ zout) {
    const int row = blockIdx.x;
    const int t   = threadIdx.x;
    const float* arow = adj + (size_t)row * NN;
    float acc = 0.0f;
#pragma unroll
    for (int c = 0; c < 8; ++c) {
        const int j = c * 1024 + t * 4;
        float4 a = *(const float4*)(arow + j);
        float4 z = *(const float4*)(zin + j);
        acc = fmaf(a.x, z.x, acc); acc = fmaf(a.y, z.y, acc);
        acc = fmaf(a.z, z.z, acc); acc = fmaf(a.w, z.w, acc);
    }
#pragma unroll
    for (int o = 32; o > 0; o >>= 1) acc += __shfl_down(acc, o);
    __shared__ float red[4];
    if ((t & 63) == 0) red[t >> 6] = acc;
    __syncthreads();
    if (t == 0) {
        const float y  = (red[0] + red[1]) + (red[2] + red[3]);
        const float dv = d[row];
        const float xn = ALPHA * dv * y + (1.0f - ALPHA) * xin[row];
        xout[row] = xn;
        zout[row] = dv * xn;
    }
}

__global__ __launch_bounds__(256) void k_mul(
        const float* __restrict__ adj, const float* __restrict__ M,
        float* __restrict__ out) {
    size_t i = ((size_t)blockIdx.x * blockDim.x + threadIdx.x) * 4;
    const size_t stride = (size_t)gridDim.x * blockDim.x * 4;
    const size_t total = (size_t)NN * NN;
    for (; i < total; i += stride) {
        float4 a = *(const float4*)(adj + i);
        float4 m = *(const float4*)(M + i);
        float4 r;
        r.x = a.x * m.x; r.y = a.y * m.y; r.z = a.z * m.z; r.w = a.w * m.w;
        *(float4*)(out + i) = r;
    }
}

__global__ __launch_bounds__(1024) void k_loss(
        const float* __restrict__ pos, const float* __restrict__ xfin,
        float* __restrict__ out) {
    const int t = threadIdx.x;
    float sn = 0.0f, sd = 0.0f;
#pragma unroll
    for (int c = 0; c < 8; ++c) {
        const int i4 = c * 1024 + t;
        float4 p = *(const float4*)(pos  + i4 * 4);
        float4 x = *(const float4*)(xfin + i4 * 4);
        sn += p.x * logf(1.0f - x.x + EPSV);
        sn += p.y * logf(1.0f - x.y + EPSV);
        sn += p.z * logf(1.0f - x.z + EPSV);
        sn += p.w * logf(1.0f - x.w + EPSV);
        sd += (p.x + p.y) + (p.z + p.w);
    }
#pragma unroll
    for (int o = 32; o > 0; o >>= 1) {
        sn += __shfl_down(sn, o);
        sd += __shfl_down(sd, o);
    }
    __shared__ float rn[16], rd[16];
    if ((t & 63) == 0) { rn[t >> 6] = sn; rd[t >> 6] = sd; }
    __syncthreads();
    if (t == 0) {
        float n = 0.0f, dd = 0.0f;
#pragma unroll
        for (int k = 0; k < 16; ++k) { n += rn[k]; dd += rd[k]; }
        out[0] = -n / dd;
    }
}

extern "C" void kernel_launch(void* const* d_in, const int* in_sizes, int n_in,
                              void* d_out, int out_size, void* d_ws, size_t ws_size,
                              hipStream_t stream) {
    const float* adj = (const float*)d_in[0];
    const float* pos = (const float*)d_in[1];
    const float* M   = (const float*)d_in[2];
    float* out = (float*)d_out;

    char* ws = (char*)d_ws;
    float* d_vec  = (float*)(ws + 0);
    float* rowsum = (float*)(ws + 32768);
    float* x_a    = (float*)(ws + 65536);
    float* x_b    = (float*)(ws + 98304);
    unsigned short* zb_a = (unsigned short*)(ws + 131072);
    unsigned short* zb_b = (unsigned short*)(ws + 163840);
    unsigned int* flags  = (unsigned int*)(ws + 196608);   // 1 KB used
    float*        accs   = (float*)(ws + 196608 + 4096);   // sn, sd, ticket
    float* zf_a   = (float*)(ws + 196608);                 // fallback reuse (exclusive paths)
    float* zf_b   = (float*)(ws + 229376);
    unsigned char* a8 = (unsigned char*)(ws + 262144);

    const size_t need_fp8 = 262144 + (size_t)NN * NN;
    const bool use_fp8 = (ws_size >= need_fp8);

    // Host-side residency check (capture-safe queries): 132KB LDS -> 1 block/CU;
    // need all 256 blocks co-resident for the flag barrier.
    static int s_chain = -1;
    if (s_chain < 0) {
        int nb = 0, ncu = 0;
        hipError_t e1 = hipOccupancyMaxActiveBlocksPerMultiprocessor(&nb, k_chain, 256, 0);
        hipError_t e2 = hipDeviceGetAttribute(&ncu, hipDeviceAttributeMultiprocessorCount, 0);
        s_chain = (e1 == hipSuccess && e2 == hipSuccess && nb >= 1 && nb * ncu >= CBLK) ? 1 : 0;
    }

    if (use_fp8) {
        k_fused_prep<<<NN, 256, 0, stream>>>(adj, M, out, a8, rowsum);
    } else {
        k_rowsum<<<NN, 256, 0, stream>>>(adj, rowsum);
    }

    if (use_fp8 && s_chain == 1) {
        hipMemsetAsync(flags, 0, 4096 + 64, stream);   // flags + accs, every replay
        k_chain<<<CBLK, 256, 0, stream>>>(a8, rowsum, pos,
                                          (unsigned int*)zb_a, (unsigned int*)zb_b,
                                          flags, accs, out + (size_t)NN * NN);
        return;
    }

    // -------- fallback: proven multi-launch path --------
    k_init<<<NN / 256, 256, 0, stream>>>(rowsum, pos, d_vec, x_a, zb_a, zf_a);
    float* xi = x_a; float* xo = x_b;
    unsigned short* zbi = zb_a; unsigned short* zbo = zb_b;
    float* zfi = zf_a; float* zfo = zf_b;
    for (int s = 0; s < STEPS; ++s) {
        if (use_fp8) {
            k_step_fp8<<<NN / 4, 256, 0, stream>>>(a8, d_vec, xi, zbi, xo, zbo);
            unsigned short* tz = zbi; zbi = zbo; zbo = tz;
        } else {
            k_step_f32<<<NN, 256, 0, stream>>>(adj, d_vec, xi, zfi, xo, zfo);
            float* tz = zfi; zfi = zfo; zfo = tz;
        }
        float* t = xi; xi = xo; xo = t;
    }
    if (!use_fp8) {
        k_mul<<<2048, 256, 0, stream>>>(adj, M, out);
    }
    k_loss<<<1, 1024, 0, stream>>>(pos, xi, out + (size_t)NN * NN);
}